// Round 1
// baseline (473.556 us; speedup 1.0000x reference)
//
#include <hip/hip_runtime.h>

#define FDIM   128
#define HEADS  4
#define ALPHA  0.2f

#define SCAN_CHUNK   1024
#define SCAN_THREADS 256

// ---------------- per-node, per-head scores: one wave per node ----------------
__global__ __launch_bounds__(256) void score_kernel(
    const float* __restrict__ x, const float* __restrict__ W,
    const float* __restrict__ a, float* __restrict__ s_src,
    float* __restrict__ s_dst, int n) {
  int lane = threadIdx.x & 63;
  int node = (blockIdx.x << 2) + (threadIdx.x >> 6);
  if (node >= n) return;
  float x0 = x[(size_t)node * FDIM + lane];
  float x1 = x[(size_t)node * FDIM + 64 + lane];
#pragma unroll
  for (int k = 0; k < HEADS; k++) {
    float h0 = x0 * W[k * FDIM + lane];
    float h1 = x1 * W[k * FDIM + 64 + lane];
    float rs = h0 * a[k * 2 * FDIM + lane]        + h1 * a[k * 2 * FDIM + 64 + lane];
    float rd = h0 * a[k * 2 * FDIM + FDIM + lane] + h1 * a[k * 2 * FDIM + FDIM + 64 + lane];
#pragma unroll
    for (int off = 32; off > 0; off >>= 1) {
      rs += __shfl_down(rs, off);
      rd += __shfl_down(rd, off);
    }
    if (lane == 0) {
      s_src[node * HEADS + k] = rs;
      s_dst[node * HEADS + k] = rd;
    }
  }
}

// ---------------- counting sort: histogram ----------------
__global__ __launch_bounds__(256) void hist_kernel(const int* __restrict__ src,
                                                   int* __restrict__ counts, int E) {
  int i = blockIdx.x * 256 + threadIdx.x;
  if (i < E) atomicAdd(&counts[src[i]], 1);
}

// ---------------- scan step 1: per-chunk sums ----------------
__global__ __launch_bounds__(SCAN_THREADS) void scan1_kernel(const int* __restrict__ counts,
                                                             int* __restrict__ partials, int n) {
  __shared__ int lds[SCAN_THREADS];
  int b = blockIdx.x, t = threadIdx.x;
  int base = b * SCAN_CHUNK + t * 4;
  int s = 0;
#pragma unroll
  for (int j = 0; j < 4; j++) {
    int i = base + j;
    s += (i < n) ? counts[i] : 0;
  }
  lds[t] = s;
  __syncthreads();
  for (int off = SCAN_THREADS / 2; off > 0; off >>= 1) {
    if (t < off) lds[t] += lds[t + off];
    __syncthreads();
  }
  if (t == 0) partials[b] = lds[0];
}

// ---------------- scan step 2: exclusive scan of chunk sums (P <= 128) ----------------
__global__ __launch_bounds__(128) void scan2_kernel(int* __restrict__ partials, int P) {
  __shared__ int lds[128];
  int t = threadIdx.x;
  int v = (t < P) ? partials[t] : 0;
  lds[t] = v;
  __syncthreads();
  for (int off = 1; off < 128; off <<= 1) {
    int xv = (t >= off) ? lds[t - off] : 0;
    __syncthreads();
    lds[t] += xv;
    __syncthreads();
  }
  if (t < P) partials[t] = lds[t] - v;  // exclusive
}

// ---------------- scan step 3: write row_ptr + cursor ----------------
__global__ __launch_bounds__(SCAN_THREADS) void scan3_kernel(
    const int* __restrict__ counts, const int* __restrict__ partials,
    int* __restrict__ row_ptr, int* __restrict__ cursor, int n, int Etot) {
  __shared__ int lds[SCAN_THREADS];
  int b = blockIdx.x, t = threadIdx.x;
  int base = b * SCAN_CHUNK + t * 4;
  int v[4];
  int s = 0;
#pragma unroll
  for (int j = 0; j < 4; j++) {
    int i = base + j;
    v[j] = (i < n) ? counts[i] : 0;
    s += v[j];
  }
  int mine = s;
  lds[t] = s;
  __syncthreads();
  for (int off = 1; off < SCAN_THREADS; off <<= 1) {
    int xv = (t >= off) ? lds[t - off] : 0;
    __syncthreads();
    lds[t] += xv;
    __syncthreads();
  }
  int run = partials[b] + (lds[t] - mine);
#pragma unroll
  for (int j = 0; j < 4; j++) {
    int i = base + j;
    if (i < n) {
      row_ptr[i] = run;
      cursor[i]  = run;
    }
    run += v[j];
  }
  if (b == 0 && t == 0) row_ptr[n] = Etot;
}

// ---------------- counting sort: scatter edges into CSR order ----------------
__global__ __launch_bounds__(256) void scatter_kernel(
    const int* __restrict__ src, const int* __restrict__ dst,
    const float* __restrict__ adj, int* __restrict__ cursor,
    int* __restrict__ dst_sorted, float* __restrict__ adj_sorted, int E) {
  int i = blockIdx.x * 256 + threadIdx.x;
  if (i >= E) return;
  int s = src[i];
  int pos = atomicAdd(&cursor[s], 1);
  dst_sorted[pos] = dst[i];
  adj_sorted[pos] = adj[i];
}

// ---------------- main aggregation: one block (128 thr) per node ----------------
__global__ __launch_bounds__(128) void aggregate_kernel(
    const float* __restrict__ x, const float* __restrict__ W,
    const float* __restrict__ s_src, const float* __restrict__ s_dst,
    const int* __restrict__ row_ptr, const int* __restrict__ dst_sorted,
    const float* __restrict__ adj_sorted, float* __restrict__ out, int n) {
  int node = blockIdx.x;
  int t = threadIdx.x;  // feature index 0..127
  int beg = row_ptr[node];
  int end = row_ptr[node + 1];

  __shared__ float se[32 * HEADS];  // e values, [edge][head]
  __shared__ int   sd[32];          // dst node ids
  __shared__ float ssrc[HEADS];
  __shared__ float srow[HEADS];
  if (t < HEADS) {
    ssrc[t] = s_src[node * HEADS + t];
    srow[t] = 0.f;
  }
  __syncthreads();

  float acc0 = 0.f, acc1 = 0.f, acc2 = 0.f, acc3 = 0.f;

  for (int c = beg; c < end; c += 32) {
    int cn = min(end - c, 32);
    int m = cn * HEADS;
    if (t < m) {
      int e = t >> 2, k = t & 3;
      int d = dst_sorted[c + e];
      if (k == 0) sd[e] = d;
      float s = ssrc[k] + s_dst[d * HEADS + k];
      s = (s >= 0.f) ? s : ALPHA * s;
      se[t] = __expf(s) * adj_sorted[c + e];
    }
    __syncthreads();
    if (t < HEADS) {
      float r = 0.f;
      for (int e2 = 0; e2 < cn; e2++) r += se[e2 * HEADS + t];
      srow[t] += r;
    }
    for (int e2 = 0; e2 < cn; e2++) {
      float xv = x[(size_t)sd[e2] * FDIM + t];
      acc0 += se[e2 * HEADS + 0] * xv;
      acc1 += se[e2 * HEADS + 1] * xv;
      acc2 += se[e2 * HEADS + 2] * xv;
      acc3 += se[e2 * HEADS + 3] * xv;
    }
    __syncthreads();
  }

  float w0 = W[0 * FDIM + t], w1 = W[1 * FDIM + t];
  float w2 = W[2 * FDIM + t], w3 = W[3 * FDIM + t];
  float o = 0.f, hp;
  hp = w0 * acc0 / srow[0]; o += (hp > 0.f) ? hp : expm1f(hp);
  hp = w1 * acc1 / srow[1]; o += (hp > 0.f) ? hp : expm1f(hp);
  hp = w2 * acc2 / srow[2]; o += (hp > 0.f) ? hp : expm1f(hp);
  hp = w3 * acc3 / srow[3]; o += (hp > 0.f) ? hp : expm1f(hp);
  out[(size_t)node * FDIM + t] = o * 0.25f;
}

extern "C" void kernel_launch(void* const* d_in, const int* in_sizes, int n_in,
                              void* d_out, int out_size, void* d_ws, size_t ws_size,
                              hipStream_t stream) {
  const float* x   = (const float*)d_in[0];
  const int*   edg = (const int*)d_in[1];
  const float* adj = (const float*)d_in[2];
  const float* W   = (const float*)d_in[3];
  const float* a   = (const float*)d_in[4];
  float* out = (float*)d_out;

  int E = in_sizes[2];
  int n = in_sizes[0] / FDIM;
  const int* src = edg;
  const int* dst = edg + E;

  // workspace carve-up (256B aligned)
  auto align = [](size_t v) { return (v + 255) & ~(size_t)255; };
  char* ws = (char*)d_ws;
  int*   counts     = (int*)ws;   ws += align((size_t)n * 4);
  int*   row_ptr    = (int*)ws;   ws += align((size_t)(n + 1) * 4);
  int*   cursor     = (int*)ws;   ws += align((size_t)n * 4);
  int*   partials   = (int*)ws;   ws += align(128 * 4);
  int*   dst_sorted = (int*)ws;   ws += align((size_t)E * 4);
  float* adj_sorted = (float*)ws; ws += align((size_t)E * 4);
  float* s_src      = (float*)ws; ws += align((size_t)n * HEADS * 4);
  float* s_dst      = (float*)ws; ws += align((size_t)n * HEADS * 4);

  int P = (n + SCAN_CHUNK - 1) / SCAN_CHUNK;  // chunks (<=128 for n<=131072)

  hipMemsetAsync(counts, 0, (size_t)n * 4, stream);

  score_kernel<<<(n + 3) / 4, 256, 0, stream>>>(x, W, a, s_src, s_dst, n);
  hist_kernel<<<(E + 255) / 256, 256, 0, stream>>>(src, counts, E);
  scan1_kernel<<<P, SCAN_THREADS, 0, stream>>>(counts, partials, n);
  scan2_kernel<<<1, 128, 0, stream>>>(partials, P);
  scan3_kernel<<<P, SCAN_THREADS, 0, stream>>>(counts, partials, row_ptr, cursor, n, E);
  scatter_kernel<<<(E + 255) / 256, 256, 0, stream>>>(src, dst, adj, cursor,
                                                      dst_sorted, adj_sorted, E);
  aggregate_kernel<<<n, 128, 0, stream>>>(x, W, s_src, s_dst, row_ptr,
                                          dst_sorted, adj_sorted, out, n);
}